// Round 7
// baseline (195.950 us; speedup 1.0000x reference)
//
#include <hip/hip_runtime.h>
#include <hip/hip_bf16.h>
#include <math.h>

#define B_   2
#define N_   2048
#define E_   1024
#define H_   16
#define D_   64
#define E3_  3072
#define M_   (B_ * N_)   // 4096

// log2(e)/8 folded into Q so softmax inner loop is a bare exp2
#define QSCALE 0.18033688011112042f

using short8  = __attribute__((ext_vector_type(8))) short;
using short4v = __attribute__((ext_vector_type(4))) short;
using f32x4   = __attribute__((ext_vector_type(4))) float;
using uint2v  = __attribute__((ext_vector_type(2))) unsigned int;
using uint4v  = __attribute__((ext_vector_type(4))) unsigned int;

#define MFMA16(a, b, c)    __builtin_amdgcn_mfma_f32_16x16x32_bf16((a), (b), (c), 0, 0, 0)

__device__ __forceinline__ unsigned short f2bf(float f) {
    __hip_bfloat16 h = __float2bfloat16(f);
    return __builtin_bit_cast(unsigned short, h);
}

__device__ __forceinline__ float fast_exp2(float x) {
#if __has_builtin(__builtin_amdgcn_exp2f)
    return __builtin_amdgcn_exp2f(x);
#else
    return exp2f(x);
#endif
}

// pack two floats to a bf16x2 dword.  gfx950 has v_cvt_pk_bf16_f32 (1 op,
// RNE); fallback = round-half-up bit trick (3 ops).
__device__ __forceinline__ unsigned int pack_bf16_2(float lo, float hi) {
#if __has_builtin(__builtin_amdgcn_cvt_pk_bf16_f32)
    auto pk = __builtin_amdgcn_cvt_pk_bf16_f32(lo, hi);
    return *(const unsigned int*)&pk;
#else
    unsigned int ulo = __builtin_bit_cast(unsigned int, lo) + 0x8000u;
    unsigned int uhi = __builtin_bit_cast(unsigned int, hi) + 0x8000u;
#if __has_builtin(__builtin_amdgcn_perm)
    return __builtin_amdgcn_perm(uhi, ulo, 0x07060302u);
#else
    return (uhi & 0xFFFF0000u) | (ulo >> 16);
#endif
#endif
}

// async global->LDS, 16B per lane
__device__ __forceinline__ void gl16(const void* g, void* l) {
    __builtin_amdgcn_global_load_lds(
        (__attribute__((address_space(1))) const void*)g,
        (__attribute__((address_space(3))) void*)l, 16, 0, 0);
}

// ---------------------------------------------------------------------------
// Kernel 0: fp32->bf16: x->xb; w_qkv row-permuted (slot s = c*1024+h*64+d) ->
// wqp; w_proj->wpb.  Block 4096: permuted (+Q-prescaled) bias -> bias_perm.
// ---------------------------------------------------------------------------
__global__ __launch_bounds__(256) void convert_kernel(
    const float* __restrict__ x, const float* __restrict__ wq,
    const float* __restrict__ wp, const float* __restrict__ b_qkv,
    unsigned short* __restrict__ xb, unsigned short* __restrict__ wqp,
    unsigned short* __restrict__ wpb, float* __restrict__ bias_perm)
{
    if (blockIdx.x == 4096) {
        for (int q = threadIdx.x; q < E3_; q += 256) {
            const int c = q >> 10, rem = q & 1023;
            const int h = rem >> 6, d = rem & 63;
            float v = b_qkv[h * 192 + d * 3 + c];
            if (c == 0) v *= QSCALE;
            bias_perm[q] = v;
        }
        return;
    }
    const int o = (blockIdx.x * 256 + threadIdx.x) * 8;
    const float* src;
    unsigned short* dst;
    if (o < 4194304) {                     // x: 4M
        src = x + o; dst = xb + o;
    } else if (o < 7340032) {              // w_qkv permuted: 3M
        const int oo = o - 4194304;
        const int s = oo >> 10, k = oo & 1023;
        const int c = s >> 10, rem = s & 1023;
        const int h = rem >> 6, d = rem & 63;
        src = wq + (size_t)(h * 192 + d * 3 + c) * E_ + k;
        dst = wqp + oo;
    } else {                               // w_proj: 1M
        const int oo = o - 7340032;
        src = wp + oo; dst = wpb + oo;
    }
    float4 a = *(const float4*)src;
    float4 b = *(const float4*)(src + 4);
    uint2v p0, p1;
    p0.x = pack_bf16_2(a.x, a.y); p0.y = pack_bf16_2(a.z, a.w);
    p1.x = pack_bf16_2(b.x, b.y); p1.y = pack_bf16_2(b.z, b.w);
    *(uint2v*)dst = p0;
    *(uint2v*)(dst + 4) = p1;
}

// ---------------------------------------------------------------------------
// GEMM plumbing: 128x128 tile, BK=32, 4 waves (2x2), global_load_lds(16B),
// XOR-swizzled LDS.
// r16 (qkv): 4-buffer pipeline, depth-2 prefetch, raw s_barrier + counted
// s_waitcnt vmcnt(4) (T4) — stage(it) is verified landed by each wave two
// iterations after issue, so the wait is ~free; prefetch loads stay in
// flight ACROSS barriers instead of the __syncthreads full vmcnt(0) drain.
// Race proof: stage(it+2) writes buf[(it+2)&3]; the only readers of that
// buffer were at iter it-2, separated by >=2 barriers; a wave's reads of
// buf[it&3] complete before it arrives at barrier_{it+1} (the MFMA lgkmcnt
// wait precedes arrival in program order), and the earliest overwrite of
// that buffer is stage(it+4) issued after barrier_{it+2}.  WAR distance
// 3 < 4 buffers.
// ---------------------------------------------------------------------------
#define GEMM_STAGE(dstA, dstB, Aglob, Bglob, k0)                             \
    {                                                                        \
        _Pragma("unroll")                                                    \
        for (int i2 = 0; i2 < 2; ++i2) {                                     \
            const int chunk = wv * 128 + i2 * 64 + lane;                     \
            const int row = chunk >> 2;                                      \
            const int gcg = (chunk & 3) ^ ((row >> 1) & 3);                  \
            const int lbase = (wv * 128 + i2 * 64) * 8;                      \
            gl16(Aglob + (size_t)(bm + row) * E_ + (k0) + gcg * 8,           \
                 &dstA[lbase]);                                              \
            gl16(Bglob + (size_t)(bn + row) * E_ + (k0) + gcg * 8,           \
                 &dstB[lbase]);                                              \
        }                                                                    \
    }

// af[i] = m-dim fragments from MARR; bf[j] = n-dim from NARR
#define GEMM_COMPUTE(MARR, NARR)                                             \
    {                                                                        \
        const int sw = (l15 >> 1) & 3;                                       \
        short8 af[4], bf[4];                                                 \
        _Pragma("unroll")                                                    \
        for (int i = 0; i < 4; ++i) {                                        \
            const int ra = wr * 64 + i * 16 + l15;                           \
            const int rb = wc * 64 + i * 16 + l15;                           \
            af[i] = *(const short8*)&MARR[ra * 32 + ((quad ^ sw) * 8)];      \
            bf[i] = *(const short8*)&NARR[rb * 32 + ((quad ^ sw) * 8)];      \
        }                                                                    \
        _Pragma("unroll")                                                    \
        for (int i = 0; i < 4; ++i)                                          \
            _Pragma("unroll")                                                \
            for (int j = 0; j < 4; ++j)                                      \
                acc[i][j] = MFMA16(af[i], bf[j], acc[i][j]);                 \
    }

#define GEMM_PROLOG                                                          \
    const int t    = threadIdx.x;                                            \
    const int wv   = t >> 6, lane = t & 63;                                  \
    const int quad = lane >> 4, l15 = lane & 15;                             \
    const int wr   = wv & 1, wc = wv >> 1;                                   \
    f32x4 acc[4][4];                                                         \
    _Pragma("unroll")                                                        \
    for (int i = 0; i < 4; ++i)                                              \
        _Pragma("unroll")                                                    \
        for (int j = 0; j < 4; ++j) acc[i][j] = (f32x4){0.f, 0.f, 0.f, 0.f};

// counted-vmcnt barrier: each wave waits for its OWN stage(it) (two iters
// old) leaving up to `n` newer VMEM ops in flight, then raw-barriers.
#define PIPE_BARRIER(n)                                                      \
    {                                                                        \
        asm volatile("s_waitcnt vmcnt(" #n ")" ::: "memory");                \
        __builtin_amdgcn_s_barrier();                                        \
        __builtin_amdgcn_sched_barrier(0);                                   \
    }

// ---------------------------------------------------------------------------
// Kernel 1: merged qkv GEMM over all 3072 output slots (grid 24 x 32).
// r13: XCD-aware block swizzle (T1), 768 = 8*96 bijective.
// r14: V-branch stores VT key-paired (slot gi*8+hi*4+j) -> attn PV at K=32.
// r16: counted-vmcnt 4-buffer pipeline (see above).
// ---------------------------------------------------------------------------
__global__ __launch_bounds__(256) void qkv_kernel(
    const unsigned short* __restrict__ A, const unsigned short* __restrict__ Bm,
    const float* __restrict__ bias_perm,
    unsigned short* __restrict__ Q, unsigned short* __restrict__ K,
    unsigned short* __restrict__ VT)
{
    __shared__ __attribute__((aligned(16))) unsigned short As[4][128 * 32];
    __shared__ __attribute__((aligned(16))) unsigned short Bs[4][128 * 32];
    GEMM_PROLOG
    // XCD swizzle: HW round-robins original linear id across 8 XCDs.
    const int lid = blockIdx.x + 24 * blockIdx.y;        // 0..767
    const int swz = (lid & 7) * 96 + (lid >> 3);         // bijective (768=8*96)
    const int bx  = swz % 24, by = swz / 24;
    const int bm = by * 128;   // token rows
    const int bn = bx * 128;   // s slots
    const int c  = bn >> 10;   // 0=Q,1=K,2=V (uniform per block)

    GEMM_STAGE(As[0], Bs[0], A, Bm, 0);
    GEMM_STAGE(As[1], Bs[1], A, Bm, 32);
    if (c < 2) {
        for (int it = 0; it < 32; ++it) {
            const int cur = it & 3;
            if (it < 31) PIPE_BARRIER(4) else PIPE_BARRIER(0);
            if (it < 30)
                GEMM_STAGE(As[(it + 2) & 3], Bs[(it + 2) & 3], A, Bm,
                           (it + 2) * 32);
            GEMM_COMPUTE(Bs[cur], As[cur]);   // D[m=s][n=token]
        }
        const float scale = (c == 0) ? QSCALE : 1.0f;
        unsigned short* dst0 = (c == 0) ? Q : K;
#pragma unroll
        for (int i = 0; i < 4; ++i) {
            const int s0 = bn + wr * 64 + i * 16 + quad * 4;
            const int h  = (s0 >> 6) & 15;
            const int d0 = s0 & 63;
            const float4 bq = *(const float4*)(bias_perm + s0);
#pragma unroll
            for (int j = 0; j < 4; ++j) {
                const int row = bm + wc * 64 + j * 16 + l15;
                const int b   = row >> 11, n = row & (N_ - 1);
                const float v0 = fmaf(acc[i][j][0], scale, bq.x);
                const float v1 = fmaf(acc[i][j][1], scale, bq.y);
                const float v2 = fmaf(acc[i][j][2], scale, bq.z);
                const float v3 = fmaf(acc[i][j][3], scale, bq.w);
                uint2v pk;
                pk.x = pack_bf16_2(v0, v1);
                pk.y = pack_bf16_2(v2, v3);
                *(uint2v*)(dst0 + (((size_t)b * H_ + h) * N_ + n) * D_ + d0) = pk;
            }
        }
    } else {
        for (int it = 0; it < 32; ++it) {
            const int cur = it & 3;
            if (it < 31) PIPE_BARRIER(4) else PIPE_BARRIER(0);
            if (it < 30)
                GEMM_STAGE(As[(it + 2) & 3], Bs[(it + 2) & 3], A, Bm,
                           (it + 2) * 32);
            GEMM_COMPUTE(As[cur], Bs[cur]);   // D[m=token][n=s]
        }
#pragma unroll
        for (int j = 0; j < 4; ++j) {
            const int s = bn + wc * 64 + j * 16 + l15;
            const int h = (s >> 6) & 15, d = s & 63;
            const float bv = bias_perm[s];
#pragma unroll
            for (int i = 0; i < 4; ++i) {
                const int row0 = bm + wr * 64 + i * 16 + quad * 4;
                const int b    = row0 >> 11, n0 = row0 & (N_ - 1);
                // r14 key-pair permutation (bijective on 4-aligned groups):
                // np = (n0 & ~31) | gi*8 + hi*4, gi = (n0>>2)&3, hi = (n0>>4)&1
                const int np = (n0 & ~31) | ((((n0 >> 2) & 3) << 3) + (((n0 >> 4) & 1) << 2));
                uint2v pk;
                pk.x = pack_bf16_2(acc[i][j][0] + bv, acc[i][j][1] + bv);
                pk.y = pack_bf16_2(acc[i][j][2] + bv, acc[i][j][3] + bv);
                *(uint2v*)(VT + (((size_t)b * H_ + h) * D_ + d) * N_ + np) = pk;
            }
        }
    }
}

// ---------------------------------------------------------------------------
// Kernel 2: flash attention, 2x2 hybrid partition (r10 sync structure —
// untouched).  Wave (wq,wk): q-rows [wq*32,+32), keys [wk*32,+32).
// S^T = K_own.Q_own; P stays in registers as the A-operand.
// r15: PV and l = P.1 at K=32 (16x16x32 A/B k-map is k = quad*8+e; the r14
// VT slot order kappa equals concat(pa[kb0], pa[kb1])).
// PV: 8 MFMAs/kt, lsum: 2, QK: 8 -> 18 passes/kt.
// LDS: 32 KB tile pool (dbuf K+V) + 512 B lsum.
// ---------------------------------------------------------------------------
__global__ __launch_bounds__(256, 3) void attn_kernel(
    const unsigned short* __restrict__ Q, const unsigned short* __restrict__ K,
    const unsigned short* __restrict__ VT, unsigned short* __restrict__ CTX)
{
    __shared__ __attribute__((aligned(16))) unsigned short pool[16384]; // Ks[2]|Vs[2]
    __shared__ float lsumBuf[2][64];   // [wk][q]

    const int t    = threadIdx.x;
    const int wv   = t >> 6, lane = t & 63;
    const int quad = lane >> 4, l15 = lane & 15;
    const int wq   = wv & 1, wk = wv >> 1;
    const int qt   = blockIdx.x & 31;   // N/64 q-tiles
    const int bh   = blockIdx.x >> 5;

    const unsigned short* Kp = K + (size_t)bh * N_ * D_;
    const unsigned short* Vp = VT + (size_t)bh * D_ * N_;

    // Q B-frags for this wave's 2 q-subtiles (global subtiles wq*2+s)
    short8 qf[2][2];
#pragma unroll
    for (int s = 0; s < 2; ++s) {
        const unsigned short* Qp =
            Q + ((size_t)bh * N_ + qt * 64 + (wq * 2 + s) * 16 + l15) * D_;
        qf[s][0] = *(const short8*)(Qp + quad * 8);
        qf[s][1] = *(const short8*)(Qp + 32 + quad * 8);
    }

    // swizzled K col-group offsets (row&7 == l15&7 for fragment rows)
    const int koff0 = (quad ^ (l15 & 7)) * 8;
    const int koff1 = ((4 + quad) ^ (l15 & 7)) * 8;
    // V b128 granule — unit (wk*4+quad) swizzled by row parity l15&7
    const int vs128 = ((wk * 4 + quad) ^ (l15 & 7)) * 8;

    // bf16 1.0 x8 for the l = P.1 MFMA (K=32)
    short8 ones8;
#pragma unroll
    for (int i = 0; i < 8; ++i) ones8[i] = (short)0x3F80;

    f32x4 O[2][4];   // [q-subtile][nt] partial over this wave's 32 keys
#pragma unroll
    for (int s = 0; s < 2; ++s)
#pragma unroll
        for (int nt = 0; nt < 4; ++nt) O[s][nt] = (f32x4){0.f, 0.f, 0.f, 0.f};
    f32x4 Lacc[2] = {{0.f, 0.f, 0.f, 0.f}, {0.f, 0.f, 0.f, 0.f}};

#define ATTN_STAGE(buf, kt)                                                  \
    {                                                                        \
        _Pragma("unroll")                                                    \
        for (int i2 = 0; i2 < 2; ++i2) {                                     \
            const int cch = (wv * 2 + i2) * 64 + lane;                       \
            const int row = cch >> 3, sg = cch & 7;                          \
            const int gc  = (sg ^ (row & 7)) * 8;                            \
            gl16(Kp + (size_t)((kt) * 64 + row) * D_ + gc,                   \
                 &pool[(buf) * 4096 + (wv * 2 + i2) * 512]);                 \
            gl16(Vp + (size_t)row * N_ + (kt) * 64 + gc,                     \
                 &pool[8192 + (buf) * 4096 + (wv * 2 + i2) * 512]);          \
        }                                                                    \
    }

    ATTN_STAGE(0, 0);

    for (int kt = 0; kt < 32; ++kt) {
        const int cur = kt & 1;
        __syncthreads();
        if (kt < 31) ATTN_STAGE(cur ^ 1, kt + 1);

        const unsigned short* Kc = pool + cur * 4096;
        const unsigned short* Vc = pool + 8192 + cur * 4096;

        // S^T per key-group kb (16 keys) x q-subtile s
        f32x4 st[2][2];
#pragma unroll
        for (int kb = 0; kb < 2; ++kb) {
            const int krow = (wk * 32 + kb * 16 + l15) * 64;
            const short8 kf0 = *(const short8*)&Kc[krow + koff0];
            const short8 kf1 = *(const short8*)&Kc[krow + koff1];
#pragma unroll
            for (int s = 0; s < 2; ++s) {
                st[kb][s] = (f32x4){0.f, 0.f, 0.f, 0.f};
                st[kb][s] = MFMA16(kf0, qf[s][0], st[kb][s]);
                st[kb][s] = MFMA16(kf1, qf[s][1], st[kb][s]);
            }
        }

        // softmax numerator: p = exp2(s), packed straight into the K=32
        // A-operand slot order: e<4 = kb0 keys quad*4+e, e>=4 = kb1 keys
        // 16+quad*4+(e-4)  (= r14 VT slot order kappa).
        short8 pa8[2];
#pragma unroll
        for (int s = 0; s < 2; ++s) {
            uint4v u;
            u.x = pack_bf16_2(fast_exp2(st[0][s][0]), fast_exp2(st[0][s][1]));
            u.y = pack_bf16_2(fast_exp2(st[0][s][2]), fast_exp2(st[0][s][3]));
            u.z = pack_bf16_2(fast_exp2(st[1][s][0]), fast_exp2(st[1][s][1]));
            u.w = pack_bf16_2(fast_exp2(st[1][s][2]), fast_exp2(st[1][s][3]));
            pa8[s] = __builtin_bit_cast(short8, u);
        }

        // l partials via MFMA (K=32): Lacc[s] += P[s] . 1
#pragma unroll
        for (int s = 0; s < 2; ++s)
            Lacc[s] = MFMA16(pa8[s], ones8, Lacc[s]);

        // PV (K=32): O[s][nt] += P[s] . V(all 32 keys of this wave);
        // one b128 read + one MFMA per (s,nt)
#pragma unroll
        for (int nt = 0; nt < 4; ++nt) {
            const short8 v8 = *(const short8*)&Vc[(nt * 16 + l15) * 64 + vs128];
#pragma unroll
            for (int s = 0; s < 2; ++s)
                O[s][nt] = MFMA16(pa8[s], v8, O[s][nt]);
        }
    }
#undef ATTN_STAGE

    // Lacc D-layout: row q_local = quad*4+g, all 16 cols identical -> lane
    // l15==0 of each quad publishes its 4 q rows.
    if (l15 == 0) {
#pragma unroll
        for (int s = 0; s < 2; ++s)
#pragma unroll
            for (int g = 0; g < 4; ++g)
                lsumBuf[wk][wq * 32 + s * 16 + quad * 4 + g] = Lacc[s][g];
    }
    __syncthreads();   // tile reads done (pool reusable) + lsumBuf visible

    // O D-layout: q = quad*4+g (row), d = nt*16 + l15 (col)
    float* red = (float*)pool;   // 8192 floats; [wq][qsub 0..31][d 0..63]
    if (wk == 1) {
#pragma unroll
        for (int s = 0; s < 2; ++s)
#pragma unroll
            for (int nt = 0; nt < 4; ++nt)
#pragma unroll
                for (int g = 0; g < 4; ++g)
                    red[wq * 2048 + (s * 16 + quad * 4 + g) * 64 + nt * 16 + l15] =
                        O[s][nt][g];
    }
    __syncthreads();

    if (wk == 0) {
        const int b = bh >> 4, h = bh & 15;
#pragma unroll
        for (int s = 0; s < 2; ++s) {
            float inv[4];
#pragma unroll
            for (int g = 0; g < 4; ++g) {
                const int q = wq * 32 + s * 16 + quad * 4 + g;
                inv[g] = 1.0f / (lsumBuf[0][q] + lsumBuf[1][q]);
            }
#pragma unroll
            for (int nt = 0; nt < 4; ++nt) {
#pragma unroll
                for (int g = 0; g < 4; ++g) {
                    const float o = O[s][nt][g] +
                        red[wq * 2048 + (s * 16 + quad * 4 + g) * 64 + nt * 16 + l15];
                    const int qrow = qt * 64 + wq * 32 + s * 16 + quad * 4 + g;
                    CTX[((size_t)b * N_ + qrow) * E_ + h * D_ + nt * 16 + l15] =
                        f2bf(o * inv[g]);
                }
            }
        }
    }
}

// ---------------------------------------------------------------------------
// Kernel 3: out = ctx @ w_proj^T + b_proj.  128(M) x 64(N) tiles -> 512
// blocks = 2/CU.  C^T orientation -> float4 stores.
// r13: XCD-aware block swizzle (T1), 512 = 8*64 bijective.
// ---------------------------------------------------------------------------
__global__ __launch_bounds__(256) void proj_kernel(
    const unsigned short* __restrict__ A, const unsigned short* __restrict__ Bm,
    const float* __restrict__ bias, float* __restrict__ out)
{
    __shared__ __attribute__((aligned(16))) unsigned short As[2][128 * 32];
    __shared__ __attribute__((aligned(16))) unsigned short Bs[2][64 * 32];
    const int t    = threadIdx.x;
    const int wv   = t >> 6, lane = t & 63;
    const int quad = lane >> 4, l15 = lane & 15;
    const int wr   = wv & 1, wc = wv >> 1;
    const int lid  = blockIdx.x + 16 * blockIdx.y;       // 0..511
    const int swz  = (lid & 7) * 64 + (lid >> 3);        // bijective (512=8*64)
    const int bx   = swz & 15, by = swz >> 4;
    const int bm   = by * 128;   // ctx rows
    const int bn   = bx * 64;    // out cols

    f32x4 acc[2][4];
#pragma unroll
    for (int i = 0; i < 2; ++i)
#pragma unroll
        for (int j = 0; j < 4; ++j) acc[i][j] = (f32x4){0.f, 0.f, 0.f, 0.f};

#define PROJ_STAGE(dstA, dstB, k0)                                           \
    {                                                                        \
        _Pragma("unroll")                                                    \
        for (int i2 = 0; i2 < 2; ++i2) {                                     \
            const int chunk = wv * 128 + i2 * 64 + lane;                     \
            const int row = chunk >> 2;                                      \
            const int gcg = (chunk & 3) ^ ((row >> 1) & 3);                  \
            gl16(A + (size_t)(bm + row) * E_ + (k0) + gcg * 8,               \
                 &dstA[(wv * 128 + i2 * 64) * 8]);                           \
        }                                                                    \
        {                                                                    \
            const int chunk = wv * 64 + lane;                                \
            const int row = chunk >> 2;                                      \
            const int gcg = (chunk & 3) ^ ((row >> 1) & 3);                  \
            gl16(Bm + (size_t)(bn + row) * E_ + (k0) + gcg * 8,              \
                 &dstB[(wv * 64) * 8]);                                      \
        }                                                                    \
    }

    PROJ_STAGE(As[0], Bs[0], 0);
    for (int it = 0; it < 32; ++it) {
        const int cur = it & 1;
        __syncthreads();
        if (it < 31) PROJ_STAGE(As[cur ^ 1], Bs[cur ^ 1], (it + 1) * 32);
        const int sw = (l15 >> 1) & 3;
        short8 af[2], bf[4];
#pragma unroll
        for (int i = 0; i < 2; ++i)
            af[i] = *(const short8*)&Bs[cur][(wr * 32 + i * 16 + l15) * 32 +
                                             ((quad ^ sw) * 8)];
#pragma unroll
        for (int j = 0; j < 4; ++j)
            bf[j] = *(const short8*)&As[cur][(wc * 64 + j * 16 + l15) * 32 +
                                             ((quad ^ sw) * 8)];
#pragma unroll
        for (int i = 0; i < 2; ++i)
#pragma unroll
            for (int j = 0; j < 4; ++j)
                acc[i][j] = MFMA16(af[i], bf[j], acc[i][j]);   // D[m=col][n=row]
    }
#undef PROJ_STAGE

#pragma unroll
    for (int i = 0; i < 2; ++i) {
        const int col0 = bn + wr * 32 + i * 16 + quad * 4;
        const float4 bp = *(const float4*)(bias + col0);
#pragma unroll
        for (int j = 0; j < 4; ++j) {
            const int row = bm + wc * 64 + j * 16 + l15;
            float4 o;
            o.x = acc[i][j][0] + bp.x;
            o.y = acc[i][j][1] + bp.y;
            o.z = acc[i][j][2] + bp.z;
            o.w = acc[i][j][3] + bp.w;
            *(float4*)(out + (size_t)row * E_ + col0) = o;
        }
    }
}

// ---------------------------------------------------------------------------
extern "C" void kernel_launch(void* const* d_in, const int* in_sizes, int n_in,
                              void* d_out, int out_size, void* d_ws, size_t ws_size,
                              hipStream_t stream)
{
    const float* x      = (const float*)d_in[0];
    const float* w_qkv  = (const float*)d_in[1];
    const float* b_qkv  = (const float*)d_in[2];
    const float* w_proj = (const float*)d_in[3];
    const float* b_proj = (const float*)d_in[4];
    float* out = (float*)d_out;

    // ws (bf16 elems): xb 4M | wqp 3M | wpb 1M | Q 4M | K 4M | VT 4M | CTX 4M
    // then bias_perm (3072 fp32)
    unsigned short* xb  = (unsigned short*)d_ws;
    unsigned short* wqp = xb  + 4194304;
    unsigned short* wpb = wqp + 3145728;
    unsigned short* Q   = wpb + 1048576;
    unsigned short* K   = Q   + 4194304;
    unsigned short* VT  = K   + 4194304;
    unsigned short* CTX = VT  + 4194304;
    float* bias_perm    = (float*)(CTX + 4194304);

    dim3 blk(256);
    convert_kernel<<<dim3(4097), blk, 0, stream>>>(
        x, w_qkv, w_proj, b_qkv, xb, wqp, wpb, bias_perm);

    qkv_kernel<<<dim3(24, 32), blk, 0, stream>>>(xb, wqp, bias_perm, Q, K, VT);

    attn_kernel<<<dim3(B_ * H_ * (N_ / 64)), blk, 0, stream>>>(Q, K, VT, CTX);

    proj_kernel<<<dim3(16, 32), blk, 0, stream>>>(CTX, wpb, b_proj, out);
}

// Round 8
// 191.188 us; speedup vs baseline: 1.0249x; 1.0249x over previous
//
#include <hip/hip_runtime.h>
#include <hip/hip_bf16.h>
#include <math.h>

#define B_   2
#define N_   2048
#define E_   1024
#define H_   16
#define D_   64
#define E3_  3072
#define M_   (B_ * N_)   // 4096

// log2(e)/8 folded into Q so softmax inner loop is a bare exp2
#define QSCALE 0.18033688011112042f

using short8  = __attribute__((ext_vector_type(8))) short;
using short4v = __attribute__((ext_vector_type(4))) short;
using f32x4   = __attribute__((ext_vector_type(4))) float;
using uint2v  = __attribute__((ext_vector_type(2))) unsigned int;
using uint4v  = __attribute__((ext_vector_type(4))) unsigned int;

#define MFMA16(a, b, c)    __builtin_amdgcn_mfma_f32_16x16x32_bf16((a), (b), (c), 0, 0, 0)

__device__ __forceinline__ unsigned short f2bf(float f) {
    __hip_bfloat16 h = __float2bfloat16(f);
    return __builtin_bit_cast(unsigned short, h);
}

__device__ __forceinline__ float fast_exp2(float x) {
#if __has_builtin(__builtin_amdgcn_exp2f)
    return __builtin_amdgcn_exp2f(x);
#else
    return exp2f(x);
#endif
}

// pack two floats to a bf16x2 dword.  gfx950 has v_cvt_pk_bf16_f32 (1 op,
// RNE); fallback = round-half-up bit trick (3 ops).
__device__ __forceinline__ unsigned int pack_bf16_2(float lo, float hi) {
#if __has_builtin(__builtin_amdgcn_cvt_pk_bf16_f32)
    auto pk = __builtin_amdgcn_cvt_pk_bf16_f32(lo, hi);
    return *(const unsigned int*)&pk;
#else
    unsigned int ulo = __builtin_bit_cast(unsigned int, lo) + 0x8000u;
    unsigned int uhi = __builtin_bit_cast(unsigned int, hi) + 0x8000u;
#if __has_builtin(__builtin_amdgcn_perm)
    return __builtin_amdgcn_perm(uhi, ulo, 0x07060302u);
#else
    return (uhi & 0xFFFF0000u) | (ulo >> 16);
#endif
#endif
}

// async global->LDS, 16B per lane
__device__ __forceinline__ void gl16(const void* g, void* l) {
    __builtin_amdgcn_global_load_lds(
        (__attribute__((address_space(1))) const void*)g,
        (__attribute__((address_space(3))) void*)l, 16, 0, 0);
}

// ---------------------------------------------------------------------------
// Kernel 0: fp32->bf16: x->xb; w_qkv row-permuted (slot s = c*1024+h*64+d) ->
// wqp; w_proj->wpb.  Block 4096: permuted (+Q-prescaled) bias -> bias_perm.
// ---------------------------------------------------------------------------
__global__ __launch_bounds__(256) void convert_kernel(
    const float* __restrict__ x, const float* __restrict__ wq,
    const float* __restrict__ wp, const float* __restrict__ b_qkv,
    unsigned short* __restrict__ xb, unsigned short* __restrict__ wqp,
    unsigned short* __restrict__ wpb, float* __restrict__ bias_perm)
{
    if (blockIdx.x == 4096) {
        for (int q = threadIdx.x; q < E3_; q += 256) {
            const int c = q >> 10, rem = q & 1023;
            const int h = rem >> 6, d = rem & 63;
            float v = b_qkv[h * 192 + d * 3 + c];
            if (c == 0) v *= QSCALE;
            bias_perm[q] = v;
        }
        return;
    }
    const int o = (blockIdx.x * 256 + threadIdx.x) * 8;
    const float* src;
    unsigned short* dst;
    if (o < 4194304) {                     // x: 4M
        src = x + o; dst = xb + o;
    } else if (o < 7340032) {              // w_qkv permuted: 3M
        const int oo = o - 4194304;
        const int s = oo >> 10, k = oo & 1023;
        const int c = s >> 10, rem = s & 1023;
        const int h = rem >> 6, d = rem & 63;
        src = wq + (size_t)(h * 192 + d * 3 + c) * E_ + k;
        dst = wqp + oo;
    } else {                               // w_proj: 1M
        const int oo = o - 7340032;
        src = wp + oo; dst = wpb + oo;
    }
    float4 a = *(const float4*)src;
    float4 b = *(const float4*)(src + 4);
    uint2v p0, p1;
    p0.x = pack_bf16_2(a.x, a.y); p0.y = pack_bf16_2(a.z, a.w);
    p1.x = pack_bf16_2(b.x, b.y); p1.y = pack_bf16_2(b.z, b.w);
    *(uint2v*)dst = p0;
    *(uint2v*)(dst + 4) = p1;
}

#define GEMM_PROLOG                                                          \
    const int t    = threadIdx.x;                                            \
    const int wv   = t >> 6, lane = t & 63;                                  \
    const int quad = lane >> 4, l15 = lane & 15;                             \
    const int wr   = wv & 1, wc = wv >> 1;                                   \
    f32x4 acc[4][4];                                                         \
    _Pragma("unroll")                                                        \
    for (int i = 0; i < 4; ++i)                                              \
        _Pragma("unroll")                                                    \
        for (int j = 0; j < 4; ++j) acc[i][j] = (f32x4){0.f, 0.f, 0.f, 0.f};

// ---------------------------------------------------------------------------
// Kernel 1: merged qkv GEMM over all 3072 output slots (grid 24 x 32).
// 128x128 tile, BK=32, 4 waves (2x2), global_load_lds(16B), XOR-swizzled
// LDS, 2-buffer ping-pong + __syncthreads (R6-verified; the R7 counted-
// vmcnt 4-buffer pipeline was time-neutral with worse FETCH -> reverted).
// r13: XCD-aware block swizzle (T1), 768 = 8*96 bijective.
// r14: V-branch stores VT key-paired (slot gi*8+hi*4+j) -> attn PV at K=32.
// r17: staging addresses hoisted to per-lane base pointers (+ it*32 per
// iter) and fragment LDS offsets precomputed — kills the per-iteration
// 64-bit address rebuild that had VALUBusy at 39%.
// ---------------------------------------------------------------------------
__global__ __launch_bounds__(256) void qkv_kernel(
    const unsigned short* __restrict__ A, const unsigned short* __restrict__ Bm,
    const float* __restrict__ bias_perm,
    unsigned short* __restrict__ Q, unsigned short* __restrict__ K,
    unsigned short* __restrict__ VT)
{
    __shared__ __attribute__((aligned(16))) unsigned short As[2][128 * 32];
    __shared__ __attribute__((aligned(16))) unsigned short Bs[2][128 * 32];
    GEMM_PROLOG
    // XCD swizzle: HW round-robins original linear id across 8 XCDs.
    const int lid = blockIdx.x + 24 * blockIdx.y;        // 0..767
    const int swz = (lid & 7) * 96 + (lid >> 3);         // bijective (768=8*96)
    const int bx  = swz % 24, by = swz / 24;
    const int bm = by * 128;   // token rows
    const int bn = bx * 128;   // s slots
    const int c  = bn >> 10;   // 0=Q,1=K,2=V (uniform per block)

    // --- r17 hoisted staging bases (identical address algebra to r13) ---
    const int chunk0 = wv * 128 + lane;
    const int row0   = chunk0 >> 2;
    const int g0     = ((chunk0 & 3) ^ ((row0 >> 1) & 3)) * 8;
    const int chunk1 = chunk0 + 64;
    const int row1   = chunk1 >> 2;
    const int g1     = ((chunk1 & 3) ^ ((row1 >> 1) & 3)) * 8;
    const unsigned short* aS0 = A  + (size_t)(bm + row0) * E_ + g0;
    const unsigned short* aS1 = A  + (size_t)(bm + row1) * E_ + g1;
    const unsigned short* bS0 = Bm + (size_t)(bn + row0) * E_ + g0;
    const unsigned short* bS1 = Bm + (size_t)(bn + row1) * E_ + g1;
    const int ldsOff0 = wv * 1024;        // shorts: (wv*128+ 0)*8
    const int ldsOff1 = wv * 1024 + 512;  // shorts: (wv*128+64)*8

#define QKV_STAGE(buf, k0)                                                   \
    {                                                                        \
        gl16(aS0 + (k0), &As[buf][ldsOff0]);                                 \
        gl16(bS0 + (k0), &Bs[buf][ldsOff0]);                                 \
        gl16(aS1 + (k0), &As[buf][ldsOff1]);                                 \
        gl16(bS1 + (k0), &Bs[buf][ldsOff1]);                                 \
    }

    // --- r17 hoisted fragment offsets (loop-invariant) ---
    const int sw = (l15 >> 1) & 3;
    int offM[4], offN[4];
#pragma unroll
    for (int i = 0; i < 4; ++i) {
        offM[i] = (wr * 64 + i * 16 + l15) * 32 + ((quad ^ sw) * 8);
        offN[i] = (wc * 64 + i * 16 + l15) * 32 + ((quad ^ sw) * 8);
    }

    QKV_STAGE(0, 0);
    if (c < 2) {
        for (int it = 0; it < 32; ++it) {
            const int cur = it & 1;
            __syncthreads();
            if (it < 31) QKV_STAGE(cur ^ 1, (it + 1) * 32);
            short8 af[4], bf[4];
#pragma unroll
            for (int i = 0; i < 4; ++i) {
                af[i] = *(const short8*)&Bs[cur][offM[i]];   // m = s slots
                bf[i] = *(const short8*)&As[cur][offN[i]];   // n = tokens
            }
#pragma unroll
            for (int i = 0; i < 4; ++i)
#pragma unroll
                for (int j = 0; j < 4; ++j)
                    acc[i][j] = MFMA16(af[i], bf[j], acc[i][j]);  // D[m=s][n=tok]
        }
        const float scale = (c == 0) ? QSCALE : 1.0f;
        unsigned short* dst0 = (c == 0) ? Q : K;
#pragma unroll
        for (int i = 0; i < 4; ++i) {
            const int s0 = bn + wr * 64 + i * 16 + quad * 4;
            const int h  = (s0 >> 6) & 15;
            const int d0 = s0 & 63;
            const float4 bq = *(const float4*)(bias_perm + s0);
#pragma unroll
            for (int j = 0; j < 4; ++j) {
                const int row = bm + wc * 64 + j * 16 + l15;
                const int b   = row >> 11, n = row & (N_ - 1);
                const float v0 = fmaf(acc[i][j][0], scale, bq.x);
                const float v1 = fmaf(acc[i][j][1], scale, bq.y);
                const float v2 = fmaf(acc[i][j][2], scale, bq.z);
                const float v3 = fmaf(acc[i][j][3], scale, bq.w);
                uint2v pk;
                pk.x = pack_bf16_2(v0, v1);
                pk.y = pack_bf16_2(v2, v3);
                *(uint2v*)(dst0 + (((size_t)b * H_ + h) * N_ + n) * D_ + d0) = pk;
            }
        }
    } else {
        for (int it = 0; it < 32; ++it) {
            const int cur = it & 1;
            __syncthreads();
            if (it < 31) QKV_STAGE(cur ^ 1, (it + 1) * 32);
            short8 af[4], bf[4];
#pragma unroll
            for (int i = 0; i < 4; ++i) {
                af[i] = *(const short8*)&As[cur][offM[i]];   // m = tokens
                bf[i] = *(const short8*)&Bs[cur][offN[i]];   // n = s slots
            }
#pragma unroll
            for (int i = 0; i < 4; ++i)
#pragma unroll
                for (int j = 0; j < 4; ++j)
                    acc[i][j] = MFMA16(af[i], bf[j], acc[i][j]);  // D[m=tok][n=s]
        }
#pragma unroll
        for (int j = 0; j < 4; ++j) {
            const int s = bn + wc * 64 + j * 16 + l15;
            const int h = (s >> 6) & 15, d = s & 63;
            const float bv = bias_perm[s];
#pragma unroll
            for (int i = 0; i < 4; ++i) {
                const int row0v = bm + wr * 64 + i * 16 + quad * 4;
                const int b     = row0v >> 11, n0 = row0v & (N_ - 1);
                // r14 key-pair permutation (bijective on 4-aligned groups):
                // np = (n0 & ~31) | gi*8 + hi*4, gi = (n0>>2)&3, hi = (n0>>4)&1
                const int np = (n0 & ~31) | ((((n0 >> 2) & 3) << 3) + (((n0 >> 4) & 1) << 2));
                uint2v pk;
                pk.x = pack_bf16_2(acc[i][j][0] + bv, acc[i][j][1] + bv);
                pk.y = pack_bf16_2(acc[i][j][2] + bv, acc[i][j][3] + bv);
                *(uint2v*)(VT + (((size_t)b * H_ + h) * D_ + d) * N_ + np) = pk;
            }
        }
    }
#undef QKV_STAGE
}

// ---------------------------------------------------------------------------
// Kernel 2: flash attention, 2x2 hybrid partition (r10 sync structure).
// Wave (wq,wk): q-rows [wq*32,+32), keys [wk*32,+32).  S^T = K_own.Q_own;
// P stays in registers as the A-operand.
// r15: PV and l = P.1 at K=32 (16x16x32 A/B k-map is k = quad*8+e; the r14
// VT slot order kappa equals concat(pa[kb0], pa[kb1])).
// r17: staging bases + inner LDS offsets hoisted out of the kt loop.
// PV: 8 MFMAs/kt, lsum: 2, QK: 8 -> 18 passes/kt.
// LDS: 32 KB tile pool (dbuf K+V) + 512 B lsum.
// ---------------------------------------------------------------------------
__global__ __launch_bounds__(256, 3) void attn_kernel(
    const unsigned short* __restrict__ Q, const unsigned short* __restrict__ K,
    const unsigned short* __restrict__ VT, unsigned short* __restrict__ CTX)
{
    __shared__ __attribute__((aligned(16))) unsigned short pool[16384]; // Ks[2]|Vs[2]
    __shared__ float lsumBuf[2][64];   // [wk][q]

    const int t    = threadIdx.x;
    const int wv   = t >> 6, lane = t & 63;
    const int quad = lane >> 4, l15 = lane & 15;
    const int wq   = wv & 1, wk = wv >> 1;
    const int qt   = blockIdx.x & 31;   // N/64 q-tiles
    const int bh   = blockIdx.x >> 5;

    const unsigned short* Kp = K + (size_t)bh * N_ * D_;
    const unsigned short* Vp = VT + (size_t)bh * D_ * N_;

    // Q B-frags for this wave's 2 q-subtiles (global subtiles wq*2+s)
    short8 qf[2][2];
#pragma unroll
    for (int s = 0; s < 2; ++s) {
        const unsigned short* Qp =
            Q + ((size_t)bh * N_ + qt * 64 + (wq * 2 + s) * 16 + l15) * D_;
        qf[s][0] = *(const short8*)(Qp + quad * 8);
        qf[s][1] = *(const short8*)(Qp + 32 + quad * 8);
    }

    // --- r17 hoisted staging bases (identical algebra to r10 macro) ---
    const int cch0 = (wv * 2) * 64 + lane;
    const int srow0 = cch0 >> 3;
    const int sgc0  = ((cch0 & 7) ^ (srow0 & 7)) * 8;
    const int cch1 = cch0 + 64;
    const int srow1 = cch1 >> 3;
    const int sgc1  = ((cch1 & 7) ^ (srow1 & 7)) * 8;
    const unsigned short* kS0 = Kp + (size_t)srow0 * D_ + sgc0;
    const unsigned short* kS1 = Kp + (size_t)srow1 * D_ + sgc1;
    const unsigned short* vS0 = Vp + (size_t)srow0 * N_ + sgc0;
    const unsigned short* vS1 = Vp + (size_t)srow1 * N_ + sgc1;
    const int aOff0 = (wv * 2) * 512, aOff1 = aOff0 + 512;

#define ATTN_STAGE(buf, kt)                                                  \
    {                                                                        \
        gl16(kS0 + (kt) * (64 * D_), &pool[(buf) * 4096 + aOff0]);           \
        gl16(vS0 + (kt) * 64,        &pool[8192 + (buf) * 4096 + aOff0]);    \
        gl16(kS1 + (kt) * (64 * D_), &pool[(buf) * 4096 + aOff1]);           \
        gl16(vS1 + (kt) * 64,        &pool[8192 + (buf) * 4096 + aOff1]);    \
    }

    // --- r17 hoisted inner LDS read offsets (loop-invariant) ---
    const int koff0 = (quad ^ (l15 & 7)) * 8;
    const int koff1 = ((4 + quad) ^ (l15 & 7)) * 8;
    const int vs128 = ((wk * 4 + quad) ^ (l15 & 7)) * 8;
    int kOff0[2], kOff1[2], vOff[4];
#pragma unroll
    for (int kb = 0; kb < 2; ++kb) {
        const int krow = (wk * 32 + kb * 16 + l15) * 64;
        kOff0[kb] = krow + koff0;
        kOff1[kb] = krow + koff1;
    }
#pragma unroll
    for (int nt = 0; nt < 4; ++nt)
        vOff[nt] = (nt * 16 + l15) * 64 + vs128;

    // bf16 1.0 x8 for the l = P.1 MFMA (K=32)
    short8 ones8;
#pragma unroll
    for (int i = 0; i < 8; ++i) ones8[i] = (short)0x3F80;

    f32x4 O[2][4];   // [q-subtile][nt] partial over this wave's 32 keys
#pragma unroll
    for (int s = 0; s < 2; ++s)
#pragma unroll
        for (int nt = 0; nt < 4; ++nt) O[s][nt] = (f32x4){0.f, 0.f, 0.f, 0.f};
    f32x4 Lacc[2] = {{0.f, 0.f, 0.f, 0.f}, {0.f, 0.f, 0.f, 0.f}};

    ATTN_STAGE(0, 0);

    for (int kt = 0; kt < 32; ++kt) {
        const int cur = kt & 1;
        __syncthreads();
        if (kt < 31) ATTN_STAGE(cur ^ 1, kt + 1);

        const unsigned short* Kc = pool + cur * 4096;
        const unsigned short* Vc = pool + 8192 + cur * 4096;

        // S^T per key-group kb (16 keys) x q-subtile s
        f32x4 st[2][2];
#pragma unroll
        for (int kb = 0; kb < 2; ++kb) {
            const short8 kf0 = *(const short8*)&Kc[kOff0[kb]];
            const short8 kf1 = *(const short8*)&Kc[kOff1[kb]];
#pragma unroll
            for (int s = 0; s < 2; ++s) {
                st[kb][s] = (f32x4){0.f, 0.f, 0.f, 0.f};
                st[kb][s] = MFMA16(kf0, qf[s][0], st[kb][s]);
                st[kb][s] = MFMA16(kf1, qf[s][1], st[kb][s]);
            }
        }

        // softmax numerator: p = exp2(s), packed straight into the K=32
        // A-operand slot order: e<4 = kb0 keys quad*4+e, e>=4 = kb1 keys
        // 16+quad*4+(e-4)  (= r14 VT slot order kappa).
        short8 pa8[2];
#pragma unroll
        for (int s = 0; s < 2; ++s) {
            uint4v u;
            u.x = pack_bf16_2(fast_exp2(st[0][s][0]), fast_exp2(st[0][s][1]));
            u.y = pack_bf16_2(fast_exp2(st[0][s][2]), fast_exp2(st[0][s][3]));
            u.z = pack_bf16_2(fast_exp2(st[1][s][0]), fast_exp2(st[1][s][1]));
            u.w = pack_bf16_2(fast_exp2(st[1][s][2]), fast_exp2(st[1][s][3]));
            pa8[s] = __builtin_bit_cast(short8, u);
        }

        // l partials via MFMA (K=32): Lacc[s] += P[s] . 1
#pragma unroll
        for (int s = 0; s < 2; ++s)
            Lacc[s] = MFMA16(pa8[s], ones8, Lacc[s]);

        // PV (K=32): O[s][nt] += P[s] . V(all 32 keys of this wave);
        // one b128 read + one MFMA per (s,nt)
#pragma unroll
        for (int nt = 0; nt < 4; ++nt) {
            const short8 v8 = *(const short8*)&Vc[vOff[nt]];
#pragma unroll
            for (int s = 0; s < 2; ++s)
                O[s][nt] = MFMA16(pa8[s], v8, O[s][nt]);
        }
    }
#undef ATTN_STAGE

    // Lacc D-layout: row q_local = quad*4+g, all 16 cols identical -> lane
    // l15==0 of each quad publishes its 4 q rows.
    if (l15 == 0) {
#pragma unroll
        for (int s = 0; s < 2; ++s)
#pragma unroll
            for (int g = 0; g < 4; ++g)
                lsumBuf[wk][wq * 32 + s * 16 + quad * 4 + g] = Lacc[s][g];
    }
    __syncthreads();   // tile reads done (pool reusable) + lsumBuf visible

    // O D-layout: q = quad*4+g (row), d = nt*16 + l15 (col)
    float* red = (float*)pool;   // 8192 floats; [wq][qsub 0..31][d 0..63]
    if (wk == 1) {
#pragma unroll
        for (int s = 0; s < 2; ++s)
#pragma unroll
            for (int nt = 0; nt < 4; ++nt)
#pragma unroll
                for (int g = 0; g < 4; ++g)
                    red[wq * 2048 + (s * 16 + quad * 4 + g) * 64 + nt * 16 + l15] =
                        O[s][nt][g];
    }
    __syncthreads();

    if (wk == 0) {
        const int b = bh >> 4, h = bh & 15;
#pragma unroll
        for (int s = 0; s < 2; ++s) {
            float inv[4];
#pragma unroll
            for (int g = 0; g < 4; ++g) {
                const int q = wq * 32 + s * 16 + quad * 4 + g;
                inv[g] = 1.0f / (lsumBuf[0][q] + lsumBuf[1][q]);
            }
#pragma unroll
            for (int nt = 0; nt < 4; ++nt) {
#pragma unroll
                for (int g = 0; g < 4; ++g) {
                    const float o = O[s][nt][g] +
                        red[wq * 2048 + (s * 16 + quad * 4 + g) * 64 + nt * 16 + l15];
                    const int qrow = qt * 64 + wq * 32 + s * 16 + quad * 4 + g;
                    CTX[((size_t)b * N_ + qrow) * E_ + h * D_ + nt * 16 + l15] =
                        f2bf(o * inv[g]);
                }
            }
        }
    }
}

// ---------------------------------------------------------------------------
// Kernel 3: out = ctx @ w_proj^T + b_proj.  128(M) x 64(N) tiles -> 512
// blocks = 2/CU.  C^T orientation -> float4 stores.
// r13: XCD-aware block swizzle (T1), 512 = 8*64 bijective.
// r17: staging bases + fragment offsets hoisted.
// ---------------------------------------------------------------------------
__global__ __launch_bounds__(256) void proj_kernel(
    const unsigned short* __restrict__ A, const unsigned short* __restrict__ Bm,
    const float* __restrict__ bias, float* __restrict__ out)
{
    __shared__ __attribute__((aligned(16))) unsigned short As[2][128 * 32];
    __shared__ __attribute__((aligned(16))) unsigned short Bs[2][64 * 32];
    const int t    = threadIdx.x;
    const int wv   = t >> 6, lane = t & 63;
    const int quad = lane >> 4, l15 = lane & 15;
    const int wr   = wv & 1, wc = wv >> 1;
    const int lid  = blockIdx.x + 16 * blockIdx.y;       // 0..511
    const int swz  = (lid & 7) * 64 + (lid >> 3);        // bijective (512=8*64)
    const int bx   = swz & 15, by = swz >> 4;
    const int bm   = by * 128;   // ctx rows
    const int bn   = bx * 64;    // out cols

    f32x4 acc[2][4];
#pragma unroll
    for (int i = 0; i < 2; ++i)
#pragma unroll
        for (int j = 0; j < 4; ++j) acc[i][j] = (f32x4){0.f, 0.f, 0.f, 0.f};

    // --- r17 hoisted staging bases ---
    const int pc0 = wv * 128 + lane, pr0 = pc0 >> 2;
    const int pg0 = ((pc0 & 3) ^ ((pr0 >> 1) & 3)) * 8;
    const int pc1 = pc0 + 64, pr1 = pc1 >> 2;
    const int pg1 = ((pc1 & 3) ^ ((pr1 >> 1) & 3)) * 8;
    const int pcB = wv * 64 + lane, prB = pcB >> 2;
    const int pgB = ((pcB & 3) ^ ((prB >> 1) & 3)) * 8;
    const unsigned short* aS0 = A  + (size_t)(bm + pr0) * E_ + pg0;
    const unsigned short* aS1 = A  + (size_t)(bm + pr1) * E_ + pg1;
    const unsigned short* bS  = Bm + (size_t)(bn + prB) * E_ + pgB;
    const int ldsA0 = wv * 1024, ldsA1 = wv * 1024 + 512, ldsB0 = wv * 512;

#define PROJ_STAGE(buf, k0)                                                  \
    {                                                                        \
        gl16(aS0 + (k0), &As[buf][ldsA0]);                                   \
        gl16(aS1 + (k0), &As[buf][ldsA1]);                                   \
        gl16(bS  + (k0), &Bs[buf][ldsB0]);                                   \
    }

    // --- r17 hoisted fragment offsets ---
    const int sw = (l15 >> 1) & 3;
    int offPM[2], offPN[4];
#pragma unroll
    for (int i = 0; i < 2; ++i)
        offPM[i] = (wr * 32 + i * 16 + l15) * 32 + ((quad ^ sw) * 8);
#pragma unroll
    for (int j = 0; j < 4; ++j)
        offPN[j] = (wc * 64 + j * 16 + l15) * 32 + ((quad ^ sw) * 8);

    PROJ_STAGE(0, 0);
    for (int it = 0; it < 32; ++it) {
        const int cur = it & 1;
        __syncthreads();
        if (it < 31) PROJ_STAGE(cur ^ 1, (it + 1) * 32);
        short8 af[2], bf[4];
#pragma unroll
        for (int i = 0; i < 2; ++i)
            af[i] = *(const short8*)&Bs[cur][offPM[i]];
#pragma unroll
        for (int j = 0; j < 4; ++j)
            bf[j] = *(const short8*)&As[cur][offPN[j]];
#pragma unroll
        for (int i = 0; i < 2; ++i)
#pragma unroll
            for (int j = 0; j < 4; ++j)
                acc[i][j] = MFMA16(af[i], bf[j], acc[i][j]);   // D[m=col][n=row]
    }
#undef PROJ_STAGE

#pragma unroll
    for (int i = 0; i < 2; ++i) {
        const int col0 = bn + wr * 32 + i * 16 + quad * 4;
        const float4 bp = *(const float4*)(bias + col0);
#pragma unroll
        for (int j = 0; j < 4; ++j) {
            const int row = bm + wc * 64 + j * 16 + l15;
            float4 o;
            o.x = acc[i][j][0] + bp.x;
            o.y = acc[i][j][1] + bp.y;
            o.z = acc[i][j][2] + bp.z;
            o.w = acc[i][j][3] + bp.w;
            *(float4*)(out + (size_t)row * E_ + col0) = o;
        }
    }
}

// ---------------------------------------------------------------------------
extern "C" void kernel_launch(void* const* d_in, const int* in_sizes, int n_in,
                              void* d_out, int out_size, void* d_ws, size_t ws_size,
                              hipStream_t stream)
{
    const float* x      = (const float*)d_in[0];
    const float* w_qkv  = (const float*)d_in[1];
    const float* b_qkv  = (const float*)d_in[2];
    const float* w_proj = (const float*)d_in[3];
    const float* b_proj = (const float*)d_in[4];
    float* out = (float*)d_out;

    // ws (bf16 elems): xb 4M | wqp 3M | wpb 1M | Q 4M | K 4M | VT 4M | CTX 4M
    // then bias_perm (3072 fp32)
    unsigned short* xb  = (unsigned short*)d_ws;
    unsigned short* wqp = xb  + 4194304;
    unsigned short* wpb = wqp + 3145728;
    unsigned short* Q   = wpb + 1048576;
    unsigned short* K   = Q   + 4194304;
    unsigned short* VT  = K   + 4194304;
    unsigned short* CTX = VT  + 4194304;
    float* bias_perm    = (float*)(CTX + 4194304);

    dim3 blk(256);
    convert_kernel<<<dim3(4097), blk, 0, stream>>>(
        x, w_qkv, w_proj, b_qkv, xb, wqp, wpb, bias_perm);

    qkv_kernel<<<dim3(24, 32), blk, 0, stream>>>(xb, wqp, bias_perm, Q, K, VT);

    attn_kernel<<<dim3(B_ * H_ * (N_ / 64)), blk, 0, stream>>>(Q, K, VT, CTX);

    proj_kernel<<<dim3(16, 32), blk, 0, stream>>>(CTX, wpb, b_proj, out);
}